// Round 16
// baseline (557.276 us; speedup 1.0000x reference)
//
#include <hip/hip_runtime.h>
#include <hip/hip_bf16.h>
#include <hip/hip_fp8.h>
#include <stdint.h>
#include <math.h>

#define HIDDEN 768
#define BATCH 4
#define SEQ 8192
#define NQ 1024
#define PHS_KS 4
#define PHS_KC (SEQ / PHS_KS)

typedef __bf16 bf16;
typedef unsigned char u8;
typedef __bf16 bf16x4 __attribute__((ext_vector_type(4)));
typedef __bf16 bf16x8 __attribute__((ext_vector_type(8)));
typedef float f32x4 __attribute__((ext_vector_type(4)));
typedef unsigned int u32x4 __attribute__((ext_vector_type(4)));

#define L2E 1.44269504088896f

#if __has_builtin(__builtin_amdgcn_exp2f)
#define EXP2(x) __builtin_amdgcn_exp2f(x)
#else
#define EXP2(x) exp2f(x)
#endif

__device__ inline u8 to_fp8(float v) {
  return (u8)__hip_cvt_float_to_fp8(v, __HIP_SATFINITE, __HIP_E4M3);
}

// General bijective XCD-chunked block-id swizzle (m204 formula, any grid size).
__device__ inline int xcd_swz() {
  const unsigned n = gridDim.x, o = blockIdx.x;
  const unsigned q = n >> 3, r = n & 7;
  const unsigned x = o & 7, k = o >> 3;
  return (int)((x < r ? x * (q + 1) : r * (q + 1) + (x - r) * q) + k);
}

#define GLOAD16(gptr, lptr)                                                   \
  __builtin_amdgcn_global_load_lds(                                           \
      (const __attribute__((address_space(1))) void*)(gptr),                  \
      (__attribute__((address_space(3))) void*)(lptr), 16, 0, 0)

#define FENCE asm volatile("" ::: "memory")
#define MFMA_BF16 __builtin_amdgcn_mfma_f32_16x16x32_bf16

// ---------------------------------------------------------------------------
// Fused prep: y=0 qu cvt, y=1 Wk+Wq cvt, y=2 Wv transpose-cvt, y=3 bqk gemv.
__global__ __launch_bounds__(256) void k_prep(
    const float* __restrict__ qu, bf16* __restrict__ qub,
    const float* __restrict__ Wk, bf16* __restrict__ Wkb,
    const float* __restrict__ Wq, bf16* __restrict__ Wqb,
    const float* __restrict__ Wv, bf16* __restrict__ WvT,
    const float* __restrict__ bq, float* __restrict__ bqk) {
  __shared__ float shm[32 * 33];
  const int t = threadIdx.x;
  const int y = blockIdx.y;

  if (y == 0) {  // qu fp32 -> bf16
    const int n4 = (int)((size_t)BATCH * NQ * HIDDEN / 4);
    const int stride = gridDim.x * 256;
    for (int i = blockIdx.x * 256 + t; i < n4; i += stride) {
      float4 v = reinterpret_cast<const float4*>(qu)[i];
      bf16x4 o = {(bf16)v.x, (bf16)v.y, (bf16)v.z, (bf16)v.w};
      reinterpret_cast<bf16x4*>(qub)[i] = o;
    }
  } else if (y == 1) {  // Wk (x<288) / Wq (x>=288) cvt
    const int n4 = HIDDEN * HIDDEN / 4;
    const float* in = blockIdx.x < 288 ? Wk : Wq;
    bf16* out = blockIdx.x < 288 ? Wkb : Wqb;
    const int xb = blockIdx.x < 288 ? blockIdx.x : blockIdx.x - 288;
    for (int i = xb * 256 + t; i < n4; i += 288 * 256) {
      float4 v = reinterpret_cast<const float4*>(in)[i];
      bf16x4 o = {(bf16)v.x, (bf16)v.y, (bf16)v.z, (bf16)v.w};
      reinterpret_cast<bf16x4*>(out)[i] = o;
    }
  } else if (y == 2) {  // Wv [H][D] -> WvT [D][H] bf16
    const int c0 = (blockIdx.x % 24) * 32, r0 = (blockIdx.x / 24) * 32;
    const int tx = t & 31, ty = t >> 5;
#pragma unroll
    for (int i = 0; i < 32; i += 8)
      shm[(ty + i) * 33 + tx] = Wv[(long)(r0 + ty + i) * HIDDEN + (c0 + tx)];
    __syncthreads();
#pragma unroll
    for (int i = 0; i < 32; i += 8)
      WvT[(long)(c0 + ty + i) * HIDDEN + (r0 + tx)] = (bf16)shm[tx * 33 + ty + i];
  } else {  // bqk[h] = sum_d bq[d]*Wk[h][d]
    if (blockIdx.x >= 192) return;
    const int h = blockIdx.x * 4 + (t >> 6);
    const int l = t & 63;
    float s = 0.0f;
#pragma unroll
    for (int d = l; d < HIDDEN; d += 64) s += bq[d] * Wk[(long)h * HIDDEN + d];
#pragma unroll
    for (int o = 32; o > 0; o >>= 1) s += __shfl_xor(s, o);
    if (l == 0) bqk[h] = s;
  }
}

// ---------------------------------------------------------------------------
// Fused: hs fp32 [B*S][H] -> hsb bf16 (same layout) + hsT fp8 e4m3 [B][H][S].
__global__ __launch_bounds__(256) void k_cvt_hs_dual(const float* __restrict__ hs,
                                                     bf16* __restrict__ hsb,
                                                     u8* __restrict__ hsT) {
  __shared__ float T[32][65];
  const int h0 = blockIdx.x * 64;
  const int s0g = blockIdx.y * 32;  // global row in [0, B*S)
  const int b = s0g >> 13;          // / 8192
  const int sIn = s0g & 8191;
  const int t = threadIdx.x;
  const int r = t >> 3, c = (t & 7) * 8;

  const float* src = hs + (long)(s0g + r) * HIDDEN + h0 + c;
  float4 v0 = *reinterpret_cast<const float4*>(src);
  float4 v1 = *reinterpret_cast<const float4*>(src + 4);
  T[r][c + 0] = v0.x; T[r][c + 1] = v0.y; T[r][c + 2] = v0.z; T[r][c + 3] = v0.w;
  T[r][c + 4] = v1.x; T[r][c + 5] = v1.y; T[r][c + 6] = v1.z; T[r][c + 7] = v1.w;

  bf16x8 o = {(bf16)v0.x, (bf16)v0.y, (bf16)v0.z, (bf16)v0.w,
              (bf16)v1.x, (bf16)v1.y, (bf16)v1.z, (bf16)v1.w};
  *reinterpret_cast<bf16x8*>(hsb + (long)(s0g + r) * HIDDEN + h0 + c) = o;

  __syncthreads();
  const int hh = t >> 2, ss = (t & 3) * 8;
  unsigned long long v8 = 0;
#pragma unroll
  for (int k = 0; k < 8; ++k)
    v8 |= (unsigned long long)to_fp8(T[ss + k][hh]) << (8 * k);
  *reinterpret_cast<unsigned long long*>(
      hsT + ((long)b * HIDDEN + h0 + hh) * SEQ + sIn + ss) = v8;
}

// ---------------------------------------------------------------------------
// Small-GEMM workhorse (round-7/13 verified): 128x128, BK=32, counted vmcnt(4),
// K-loop LDS swizzle, group-swizzled bf16 bounce epilogue / direct fp32 stores.
template <typename OUT>
__global__ __launch_bounds__(256) void k_gemm_bt(
    const bf16* __restrict__ A, const bf16* __restrict__ B, OUT* __restrict__ C,
    const float* __restrict__ bias, int N, int K, float scale,
    int nx, int ny, long strA, long strB, long strC) {
  const int id = xcd_swz();
  const int col = id % nx;
  const int row = (id / nx) % ny;
  const int z = id / (nx * ny);

  __shared__ bf16 smem[16384];

  const int tid = threadIdx.x;
  const int lane = tid & 63, wave = tid >> 6;
  const int wr = wave >> 1, wc = wave & 1;
  const int lr = lane & 15, l16 = lane >> 4, lg = (lane >> 4) * 4;
  const int sl = (l16 ^ (lr & 3) ^ ((lr >> 2) & 3)) * 8;

  const bf16* At = A + (long)z * strA + (long)row * 128 * K;
  const bf16* Bt = B + (long)z * strB + (long)col * 128 * K;

#define STAGE_TILE(buf, k0)                                                   \
  {                                                                           \
    bf16* dA = smem + (buf) * 4096;                                           \
    bf16* dB = smem + 8192 + (buf) * 4096;                                    \
    _Pragma("unroll") for (int h = 0; h < 2; ++h) {                           \
      const int cch = tid + h * 256;                                          \
      const int rr = cch >> 2;                                                \
      const int src = ((cch & 3) ^ (rr & 3) ^ ((rr >> 2) & 3)) * 8;           \
      GLOAD16(At + (long)rr * K + (k0) + src, (char*)dA + cch * 16);          \
      GLOAD16(Bt + (long)rr * K + (k0) + src, (char*)dB + cch * 16);          \
    }                                                                         \
  }

  STAGE_TILE(0, 0);

  f32x4 acc[4][4] = {};
  const int nt = K / 32;
  int cur = 0;
#pragma unroll 1
  for (int t = 0; t < nt; ++t) {
    FENCE;
    __builtin_amdgcn_s_barrier();
    FENCE;
    if (t + 1 < nt) {
      STAGE_TILE(cur ^ 1, (t + 1) * 32);
      asm volatile("s_waitcnt vmcnt(4)" ::: "memory");
    } else {
      asm volatile("s_waitcnt vmcnt(0)" ::: "memory");
    }
    __builtin_amdgcn_s_barrier();
    FENCE;
    const bf16* rA = smem + cur * 4096;
    const bf16* rB = smem + 8192 + cur * 4096;
    bf16x8 af[4], bfr[4];
#pragma unroll
    for (int m = 0; m < 4; ++m)
      af[m] = *reinterpret_cast<const bf16x8*>(&rA[(wr * 64 + m * 16 + lr) * 32 + sl]);
#pragma unroll
    for (int n = 0; n < 4; ++n)
      bfr[n] = *reinterpret_cast<const bf16x8*>(&rB[(wc * 64 + n * 16 + lr) * 32 + sl]);
    __builtin_amdgcn_s_setprio(1);
#pragma unroll
    for (int m = 0; m < 4; ++m)
#pragma unroll
      for (int n = 0; n < 4; ++n)
        acc[m][n] = MFMA_BF16(af[m], bfr[n], acc[m][n], 0, 0, 0);
    __builtin_amdgcn_s_setprio(0);
    cur ^= 1;
  }
#undef STAGE_TILE

  if constexpr (__is_same(OUT, float)) {
    float* Cb = (float*)C + (long)z * strC;
#pragma unroll
    for (int m = 0; m < 4; ++m)
#pragma unroll
      for (int n = 0; n < 4; ++n) {
        const int gc = col * 128 + wc * 64 + n * 16 + lr;
        const float bv = bias ? bias[gc] : 0.0f;
#pragma unroll
        for (int j = 0; j < 4; ++j) {
          const int gr = row * 128 + wr * 64 + m * 16 + lg + j;
          Cb[(long)gr * N + gc] = acc[m][n][j] * scale + bv;
        }
      }
  } else {
    FENCE;
    __builtin_amdgcn_s_barrier();
    FENCE;
#pragma unroll
    for (int m = 0; m < 4; ++m)
#pragma unroll
      for (int n = 0; n < 4; ++n) {
        const int gc = col * 128 + wc * 64 + n * 16 + lr;
        const float bv = bias ? bias[gc] : 0.0f;
#pragma unroll
        for (int j = 0; j < 4; ++j) {
          const int prow = wr * 64 + m * 16 + lg + j;
          const int pcol = (wc * 64 + n * 16 + lr) ^ (l16 << 4);
          smem[prow * 128 + pcol] = (bf16)(acc[m][n][j] * scale + bv);
        }
      }
    __syncthreads();
    OUT* Cb = C + (long)z * strC;
    const long rb = (long)row * 128, cb = (long)col * 128;
#pragma unroll
    for (int i = 0; i < 8; ++i) {
      const int ch = tid + i * 256;
      const int rr = ch >> 4;
      const int ce = (ch & 15) * 8;
      const int lcol = ce ^ (((rr >> 2) & 3) << 4);
      *reinterpret_cast<bf16x8*>(&Cb[(rb + rr) * N + cb + lcol]) =
          *reinterpret_cast<const bf16x8*>(smem + ch * 8);
    }
  }
}

// ---------------------------------------------------------------------------
// SCORES 256x256, BK=32, 8 waves (2M x 4N), LDS 64KB double-buffered ->
// 2 blocks/CU, 4 waves/SIMD (cross-block overlap hides barrier stalls).
// K-loop: r7/r15-proven sync — {barrier | stage full next tile (4 loads/thr)
// | vmcnt(4): oldest 4 = tile t resident, t+1 in flight | barrier | 32 MFMA}.
// Swizzle (BK=32 rows = 64B = 4 chunks, derived + bank-traced): banks split
// lanes by lr parity into two 4-bank sets of 8 lanes -> s(r) = (r>>1)&3
// covers 0..3 twice per parity class -> 2-way (free). Fragment rows =
// 16k + lr -> read key = l16 ^ ((lr>>1)&3), lane-constant. Source-side
// inverse on gload, dest linear (rule #21).
__global__ __launch_bounds__(512, 4) void k_score256(
    const bf16* __restrict__ A, const bf16* __restrict__ B, u8* __restrict__ Pr,
    const float* __restrict__ mask, float* __restrict__ rspart, float scale) {
  __shared__ char smem[65536];  // A 2x16KB @0, B 2x16KB @32768
  const int tid = threadIdx.x;
  const int lane = tid & 63, wave = tid >> 6;
  const int wm = wave >> 2, wn = wave & 3;   // 2M x 4N wave grid
  const int lr = lane & 15, l16 = lane >> 4;

  const int id = xcd_swz();                  // 512 = 4 rows x 32 cols x 4 z
  const int row = id & 3;
  const int col = (id >> 2) & 31;
  const int z = id >> 7;
  const bf16* Ap = A + ((long)z * NQ + row * 256) * HIDDEN;
  const bf16* Bp = B + ((long)z * SEQ + col * 256) * HIDDEN;

  const int pc = (l16 ^ ((lr >> 1) & 3)) * 16;  // physical chunk byte-offset

  // stage the full 256x32 A and B tiles for one K-step (4 loads/thread)
  auto STG_ALL = [&](int buf, int k0) {
    char* dA = smem + buf * 16384;
    char* dB = smem + 32768 + buf * 16384;
#pragma unroll
    for (int h = 0; h < 2; ++h) {
      const int c = tid + h * 512;            // 1024 chunks of 16B each
      const int r = c >> 2;                   // row 0..255
      const int l = (c & 3) ^ ((r >> 1) & 3); // logical chunk for dest chunk c&3
      GLOAD16(Ap + (long)r * HIDDEN + k0 + l * 8, dA + c * 16);
      GLOAD16(Bp + (long)r * HIDDEN + k0 + l * 8, dB + c * 16);
    }
  };

  f32x4 acc[8][4] = {};
  const int NT = HIDDEN / 32;  // 24
  STG_ALL(0, 0);

#pragma unroll 1
  for (int t = 0; t < NT; ++t) {
    FENCE;
    __builtin_amdgcn_s_barrier();  // reads of tile t-1 done -> its buffer free
    FENCE;
    if (t + 1 < NT) {
      STG_ALL((t + 1) & 1, (t + 1) * 32);
      asm volatile("s_waitcnt vmcnt(4)" ::: "memory");  // tile t fully resident
    } else {
      asm volatile("s_waitcnt vmcnt(0)" ::: "memory");
    }
    __builtin_amdgcn_s_barrier();  // every thread sees tile t
    FENCE;
    const char* sA = smem + (t & 1) * 16384;
    const char* sB = smem + 32768 + (t & 1) * 16384;
    bf16x8 af[4], bfv[4];
#pragma unroll
    for (int n = 0; n < 4; ++n)
      bfv[n] = *reinterpret_cast<const bf16x8*>(
          sB + (wn * 64 + n * 16 + lr) * 64 + pc);
#pragma unroll
    for (int mh = 0; mh < 2; ++mh) {
#pragma unroll
      for (int m = 0; m < 4; ++m)
        af[m] = *reinterpret_cast<const bf16x8*>(
            sA + (wm * 128 + mh * 64 + m * 16 + lr) * 64 + pc);
      __builtin_amdgcn_s_setprio(1);
#pragma unroll
      for (int m = 0; m < 4; ++m)
#pragma unroll
        for (int n = 0; n < 4; ++n)
          acc[mh * 4 + m][n] = MFMA_BF16(af[m], bfv[n], acc[mh * 4 + m][n], 0, 0, 0);
      __builtin_amdgcn_s_setprio(0);
    }
  }

  // ---- epilogue: exp2 + fp8, rowsum partials, group-swizzled LDS bounce ----
  __syncthreads();  // all compute reads of smem done before reuse as C tile
  u8* sm8 = (u8*)smem;  // 256x256 u8 = 64KB, fits exactly
  const float sL = scale * L2E;
  float mb[4];
#pragma unroll
  for (int n = 0; n < 4; ++n) {
    const int gc = col * 256 + wn * 64 + n * 16 + lr;
    mb[n] = (1.0f - mask[(long)z * SEQ + gc]) * (-10000.0f * L2E);
  }
  float rsv[8][4];
#pragma unroll
  for (int m = 0; m < 8; ++m)
#pragma unroll
    for (int j = 0; j < 4; ++j) rsv[m][j] = 0.0f;
#pragma unroll
  for (int m = 0; m < 8; ++m)
#pragma unroll
    for (int n = 0; n < 4; ++n)
#pragma unroll
      for (int j = 0; j < 4; ++j) {
        const float v = EXP2(fmaf(acc[m][n][j], sL, mb[n]));
        rsv[m][j] += v;
        const int prow = wm * 128 + m * 16 + l16 * 4 + j;
        const int pcol = (wn * 64 + n * 16 + lr) ^ (l16 << 5);
        sm8[prow * 256 + pcol] = to_fp8(v);
      }
#pragma unroll
  for (int m = 0; m < 8; ++m)
#pragma unroll
    for (int j = 0; j < 4; ++j) {
      float v = rsv[m][j];
      v += __shfl_xor(v, 1); v += __shfl_xor(v, 2);
      v += __shfl_xor(v, 4); v += __shfl_xor(v, 8);
      if (lr == 0) {
        const int gr = row * 256 + wm * 128 + m * 16 + l16 * 4 + j;
        rspart[((long)z * NQ + gr) * 128 + col * 4 + wn] = v;
      }
    }
  __syncthreads();
  u8* Cb = Pr + ((long)z * NQ + row * 256) * SEQ + (long)col * 256;
#pragma unroll
  for (int i = 0; i < 8; ++i) {
    const int ch = tid + i * 512;   // 4096 chunks of 16B = 256x256 u8
    const int rr = ch >> 4;
    const int ce = (ch & 15) * 16;
    const int lcol = ce ^ (((rr >> 2) & 3) << 5);
    *reinterpret_cast<u32x4*>(&Cb[(long)rr * SEQ + lcol]) =
        *reinterpret_cast<const u32x4*>(sm8 + ch * 16);
  }
}

// rowsum[row] = sum of 128 partial slots (deterministic reduce)
__global__ __launch_bounds__(256) void k_rowsum(const float* __restrict__ rp,
                                                float* __restrict__ rs) {
  const int t = threadIdx.x;
  const int row = blockIdx.x * 8 + (t >> 5);
  const int s = t & 31;
  const float* base = rp + (long)row * 128;
  float v = base[s] + base[s + 32] + base[s + 64] + base[s + 96];
  v += __shfl_xor(v, 1); v += __shfl_xor(v, 2); v += __shfl_xor(v, 4);
  v += __shfl_xor(v, 8); v += __shfl_xor(v, 16);
  if (s == 0) rs[row] = v;
}

// ---------------------------------------------------------------------------
// PHS split-K partial GEMM (FP8): Cpart[kc][b,q,:] = P8[b,q-tile,kc] . hsT8^T
// 128x128 tile, BK=32, mfma_f32_16x16x32_fp8_fp8; counted vmcnt(2).
__global__ __launch_bounds__(256) void k_gemm_phs(const u8* __restrict__ P,
                                                  const u8* __restrict__ HT,
                                                  bf16* __restrict__ Cp) {
  const int id = xcd_swz();
  const int col = id % 6;
  int r = id / 6;
  const int row = r % 8;
  r /= 8;
  const int b = r % 4;
  const int kc = r / 4;

  __shared__ char smem[32768];
  u8* sm8 = (u8*)smem;

  const int tid = threadIdx.x;
  const int lane = tid & 63, wave = tid >> 6;
  const int wr = wave >> 1, wc = wave & 1;
  const int lr = lane & 15, l16 = lane >> 4;
  const int lg = l16 * 4;
  const int ps = (((l16 >> 1) ^ ((lr >> 2) & 1)) * 16) + (l16 & 1) * 8;

  const u8* At = P + (long)b * NQ * SEQ + (long)row * 128 * SEQ + (long)kc * PHS_KC;
  const u8* Bt = HT + ((long)b * HIDDEN + (long)col * 128) * SEQ + (long)kc * PHS_KC;

#define STAGE_P8(buf, k0)                                                     \
  {                                                                           \
    u8* dA = sm8 + (buf) * 4096;                                              \
    u8* dB = sm8 + 8192 + (buf) * 4096;                                       \
    const int rr = tid >> 1;                                                  \
    const int src = ((tid & 1) ^ ((rr >> 2) & 1)) * 16;                       \
    GLOAD16(At + (long)rr * SEQ + (k0) + src, dA + tid * 16);                 \
    GLOAD16(Bt + (long)rr * SEQ + (k0) + src, dB + tid * 16);                 \
  }

  const int nt = PHS_KC / 32;  // 64
  STAGE_P8(0, 0);

  f32x4 acc[4][4] = {};
#pragma unroll 1
  for (int t = 0; t < nt; ++t) {
    FENCE;
    __builtin_amdgcn_s_barrier();
    FENCE;
    if (t + 1 < nt) {
      STAGE_P8((t + 1) & 1, (t + 1) * 32);
      asm volatile("s_waitcnt vmcnt(2)" ::: "memory");
    } else {
      asm volatile("s_waitcnt vmcnt(0)" ::: "memory");
    }
    __builtin_amdgcn_s_barrier();
    FENCE;
    const u8* rA = sm8 + (t & 1) * 4096;
    const u8* rB = sm8 + 8192 + (t & 1) * 4096;
    long af[4], bfr[4];
#pragma unroll
    for (int m = 0; m < 4; ++m)
      af[m] = *reinterpret_cast<const long*>(rA + (wr * 64 + m * 16 + lr) * 32 + ps);
#pragma unroll
    for (int n = 0; n < 4; ++n)
      bfr[n] = *reinterpret_cast<const long*>(rB + (wc * 64 + n * 16 + lr) * 32 + ps);
    __builtin_amdgcn_s_setprio(1);
#pragma unroll
    for (int m = 0; m < 4; ++m)
#pragma unroll
      for (int n = 0; n < 4; ++n)
        acc[m][n] = __builtin_amdgcn_mfma_f32_16x16x32_fp8_fp8(af[m], bfr[n], acc[m][n], 0, 0, 0);
    __builtin_amdgcn_s_setprio(0);
  }
#undef STAGE_P8

  FENCE;
  __builtin_amdgcn_s_barrier();
  FENCE;
  bf16* smb = (bf16*)smem;
#pragma unroll
  for (int m = 0; m < 4; ++m)
#pragma unroll
    for (int n = 0; n < 4; ++n)
#pragma unroll
      for (int j = 0; j < 4; ++j) {
        const int prow = wr * 64 + m * 16 + lg + j;
        const int pcol = (wc * 64 + n * 16 + lr) ^ (l16 << 4);
        smb[prow * 128 + pcol] = (bf16)acc[m][n][j];
      }
  __syncthreads();
  bf16* Co = Cp + ((long)kc * BATCH + b) * NQ * HIDDEN;
  const long rb = (long)row * 128, cb = (long)col * 128;
#pragma unroll
  for (int i = 0; i < 8; ++i) {
    const int ch = tid + i * 256;
    const int rr = ch >> 4;
    const int ce = (ch & 15) * 8;
    const int lcol = ce ^ (((rr >> 2) & 3) << 4);
    *reinterpret_cast<bf16x8*>(&Co[(rb + rr) * HIDDEN + cb + lcol]) =
        *reinterpret_cast<const bf16x8*>(smb + ch * 8);
  }
}

// ---------------------------------------------------------------------------
// V-fold with inline partial-reduce + normalize:
// out[q,:] = ((sum_kc Ppart[kc][q,:]) / rowsum[q]) . Wv + bv
__global__ __launch_bounds__(256) void k_vfold(const bf16* __restrict__ Pp,
                                               const float* __restrict__ rs,
                                               const bf16* __restrict__ WvT,
                                               const float* __restrict__ bias,
                                               float* __restrict__ out) {
  const int id = xcd_swz();
  const int col = id % 6;
  const int row = id / 6;

  __shared__ bf16 smem[16384];

  const int tid = threadIdx.x;
  const int lane = tid & 63, wave = tid >> 6;
  const int wr = wave >> 1, wc = wave & 1;
  const int lr = lane & 15, l16 = lane >> 4, lg = (lane >> 4) * 4;
  const int sl = (l16 ^ (lr & 3) ^ ((lr >> 2) & 3)) * 8;

  const long NB = (long)BATCH * NQ * HIDDEN;
  const bf16* At = Pp + (long)row * 128 * HIDDEN;
  const bf16* Bt = WvT + (long)col * 128 * HIDDEN;
  const float inv0 = 1.0f / rs[row * 128 + (tid >> 2)];
  const float inv1 = 1.0f / rs[row * 128 + 64 + (tid >> 2)];

  auto STAGE = [&](int buf, int k0) {
    bf16* dA = smem + buf * 4096;
    bf16* dB = smem + 8192 + buf * 4096;
#pragma unroll
    for (int h = 0; h < 2; ++h) {
      const int c = tid + h * 256;
      const int rr = c >> 2;
      const int swz = ((c & 3) ^ (rr & 3) ^ ((rr >> 2) & 3)) * 8;
      const int cc = (c & 3) * 8;
      float s8[8] = {};
#pragma unroll
      for (int kc = 0; kc < PHS_KS; ++kc) {
        bf16x8 v = *reinterpret_cast<const bf16x8*>(
            At + (long)kc * NB + (long)rr * HIDDEN + k0 + cc);
#pragma unroll
        for (int j = 0; j < 8; ++j) s8[j] += (float)v[j];
      }
      const float inv = h ? inv1 : inv0;
      bf16x8 o;
#pragma unroll
      for (int j = 0; j < 8; ++j) o[j] = (bf16)(s8[j] * inv);
      *reinterpret_cast<bf16x8*>(dA + rr * 32 + swz) = o;
      GLOAD16(Bt + (long)rr * HIDDEN + k0 + swz, (char*)dB + c * 16);
    }
  };

  const int nt = HIDDEN / 32;  // 24
  STAGE(0, 0);
  __syncthreads();

  f32x4 acc[4][4] = {};
  int cur = 0;
#pragma unroll 1
  for (int t = 0; t < nt; ++t) {
    if (t + 1 < nt) STAGE(cur ^ 1, (t + 1) * 32);
    const bf16* rA = smem + cur * 4096;
    const bf16* rB = smem + 8192 + cur * 4096;
    bf16x8 af[4], bfr[4];
#pragma unroll
    for (int m = 0; m < 4; ++m)
      af[m] = *reinterpret_cast<const bf16x8*>(&rA[(wr * 64 + m * 16 + lr) * 32 + sl]);
#pragma unroll
    for (int n = 0; n < 4; ++n)
      bfr[n] = *reinterpret_cast<const bf16x8*>(&rB[(wc * 64 + n * 16 + lr) * 32 + sl]);
#pragma unroll
    for (int m = 0; m < 4; ++m)
#pragma unroll
      for (int n = 0; n < 4; ++n)
        acc[m][n] = MFMA_BF16(af[m], bfr[n], acc[m][n], 0, 0, 0);
    __syncthreads();
    cur ^= 1;
  }

#pragma unroll
  for (int m = 0; m < 4; ++m)
#pragma unroll
    for (int n = 0; n < 4; ++n) {
      const int gc = col * 128 + wc * 64 + n * 16 + lr;
      const float bv = bias[gc];
#pragma unroll
      for (int j = 0; j < 4; ++j) {
        const int gr = row * 128 + wr * 64 + m * 16 + lg + j;
        out[(long)gr * HIDDEN + gc] = acc[m][n][j] + bv;
      }
    }
}

// ---------------------------------------------------------------------------
extern "C" void kernel_launch(void* const* d_in, const int* in_sizes, int n_in,
                              void* d_out, int out_size, void* d_ws, size_t ws_size,
                              hipStream_t stream) {
  const float* hs = (const float*)d_in[0];    // [B,S,H]
  const float* qu = (const float*)d_in[1];    // [B,Q,H]
  const float* mask = (const float*)d_in[2];  // [B,S]
  const float* Wq = (const float*)d_in[3];
  const float* bq = (const float*)d_in[4];
  const float* Wk = (const float*)d_in[5];
  const float* Wv = (const float*)d_in[7];
  const float* bv = (const float*)d_in[8];
  float* out = (float*)d_out;  // [B,Q,H] fp32
  // bk (d_in[6]) adds a softmax-row-constant -> cancels exactly.

  const size_t HS_N = (size_t)BATCH * SEQ * HIDDEN;
  const size_t QU_N = (size_t)BATCH * NQ * HIDDEN;
  const size_t W_N = (size_t)HIDDEN * HIDDEN;
  const size_t P_N = (size_t)BATCH * NQ * SEQ;

  char* ws = (char*)d_ws;
  size_t off = 0;
  auto alloc = [&](size_t bytes) {
    char* p = ws + off;
    off += (bytes + 255) & ~(size_t)255;
    return p;
  };

  // regionA: hsb (live through scores) / PHS partials (after) — overlap
  char* regionA = alloc(HS_N * 2);
  bf16* hsb = (bf16*)regionA;
  bf16* Ppart = (bf16*)regionA;        // PHS_KS(4) * QU_N bf16 = 25.2 MB
  u8* hsT8 = (u8*)alloc(HS_N);         // [B][H][S] fp8 e4m3
  u8* Pr = (u8*)alloc(P_N);            // unnormalized probs exp(s+mb), fp8
  bf16* qub = (bf16*)alloc(QU_N * 2);
  bf16* tmpb = (bf16*)alloc(QU_N * 2); // folded query: qu.(Wq.Wk^T) + bq.Wk^T
  bf16* Wkb = (bf16*)alloc(W_N * 2);
  bf16* Wqb = (bf16*)alloc(W_N * 2);
  bf16* WvT = (bf16*)alloc(W_N * 2);
  bf16* Mt = (bf16*)alloc(W_N * 2);    // Wk.Wq^T
  float* bqk = (float*)alloc(HIDDEN * 4);
  float* rspart = (float*)alloc((size_t)BATCH * NQ * 128 * 4);  // 2 MB
  float* rowsum = (float*)alloc((size_t)BATCH * NQ * 4);

  // 1) fused prep (qu cvt, Wk/Wq cvt, Wv transpose, bqk gemv) + hs prep
  k_prep<<<dim3(576, 4), dim3(256), 0, stream>>>(qu, qub, Wk, Wkb, Wq, Wqb,
                                                 Wv, WvT, bq, bqk);
  k_cvt_hs_dual<<<dim3(12, 1024), dim3(256), 0, stream>>>(hs, hsb, hsT8);

  // 2) Mt = Wk.Wq^T  [768x768]
  k_gemm_bt<bf16><<<dim3(36), dim3(256), 0, stream>>>(
      Wkb, Wqb, Mt, nullptr, HIDDEN, HIDDEN, 1.0f, 6, 6, 0, 0, 0);

  // 3) folded query: tmp = qub.Mt^T + bqk  [4096x768]
  k_gemm_bt<bf16><<<dim3(192), dim3(256), 0, stream>>>(
      qub, Mt, tmpb, bqk, HIDDEN, HIDDEN, 1.0f, 6, 32, 0, 0, 0);

  // 4) scores (256x256, BK=32, 2 blocks/CU): Pr(fp8) = exp2(...), rowsum partials
  const float qkscale = 1.0f / sqrtf((float)HIDDEN);
  k_score256<<<dim3(512), dim3(512), 0, stream>>>(tmpb, hsb, Pr, mask, rspart, qkscale);
  k_rowsum<<<dim3(BATCH * NQ / 8), dim3(256), 0, stream>>>(rspart, rowsum);

  // 5) PHS partials (fp8 MFMA): Ppart[kc] = P8[:, kc-chunk] . hsT8^T
  k_gemm_phs<<<dim3(6 * 8 * 4 * PHS_KS), dim3(256), 0, stream>>>(Pr, hsT8, Ppart);

  // 6) V-fold with inline reduce+normalize: out = ((sum Ppart)/rowsum).Wv + bv
  k_vfold<<<dim3(192), dim3(256), 0, stream>>>(Ppart, rowsum, WvT, bv, out);
}

// Round 17
// 230.259 us; speedup vs baseline: 2.4202x; 2.4202x over previous
//
#include <hip/hip_runtime.h>
#include <hip/hip_bf16.h>
#include <hip/hip_fp8.h>
#include <stdint.h>
#include <math.h>

#define HIDDEN 768
#define BATCH 4
#define SEQ 8192
#define NQ 1024
#define PHS_KS 4
#define PHS_KC (SEQ / PHS_KS)

typedef __bf16 bf16;
typedef unsigned char u8;
typedef __bf16 bf16x4 __attribute__((ext_vector_type(4)));
typedef __bf16 bf16x8 __attribute__((ext_vector_type(8)));
typedef float f32x4 __attribute__((ext_vector_type(4)));
typedef unsigned int u32x4 __attribute__((ext_vector_type(4)));

#define L2E 1.44269504088896f

#if __has_builtin(__builtin_amdgcn_exp2f)
#define EXP2(x) __builtin_amdgcn_exp2f(x)
#else
#define EXP2(x) exp2f(x)
#endif

__device__ inline u8 to_fp8(float v) {
  return (u8)__hip_cvt_float_to_fp8(v, __HIP_SATFINITE, __HIP_E4M3);
}

// General bijective XCD-chunked block-id swizzle (m204 formula, any grid size).
__device__ inline int xcd_swz() {
  const unsigned n = gridDim.x, o = blockIdx.x;
  const unsigned q = n >> 3, r = n & 7;
  const unsigned x = o & 7, k = o >> 3;
  return (int)((x < r ? x * (q + 1) : r * (q + 1) + (x - r) * q) + k);
}

#define GLOAD16(gptr, lptr)                                                   \
  __builtin_amdgcn_global_load_lds(                                           \
      (const __attribute__((address_space(1))) void*)(gptr),                  \
      (__attribute__((address_space(3))) void*)(lptr), 16, 0, 0)

#define FENCE asm volatile("" ::: "memory")
#define MFMA_BF16 __builtin_amdgcn_mfma_f32_16x16x32_bf16

// ---------------------------------------------------------------------------
// Fused prep: y=0 qu cvt, y=1 Wk+Wq cvt, y=2 Wv transpose-cvt, y=3 bqk gemv.
__global__ __launch_bounds__(256) void k_prep(
    const float* __restrict__ qu, bf16* __restrict__ qub,
    const float* __restrict__ Wk, bf16* __restrict__ Wkb,
    const float* __restrict__ Wq, bf16* __restrict__ Wqb,
    const float* __restrict__ Wv, bf16* __restrict__ WvT,
    const float* __restrict__ bq, float* __restrict__ bqk) {
  __shared__ float shm[32 * 33];
  const int t = threadIdx.x;
  const int y = blockIdx.y;

  if (y == 0) {  // qu fp32 -> bf16
    const int n4 = (int)((size_t)BATCH * NQ * HIDDEN / 4);
    const int stride = gridDim.x * 256;
    for (int i = blockIdx.x * 256 + t; i < n4; i += stride) {
      float4 v = reinterpret_cast<const float4*>(qu)[i];
      bf16x4 o = {(bf16)v.x, (bf16)v.y, (bf16)v.z, (bf16)v.w};
      reinterpret_cast<bf16x4*>(qub)[i] = o;
    }
  } else if (y == 1) {  // Wk (x<288) / Wq (x>=288) cvt
    const int n4 = HIDDEN * HIDDEN / 4;
    const float* in = blockIdx.x < 288 ? Wk : Wq;
    bf16* out = blockIdx.x < 288 ? Wkb : Wqb;
    const int xb = blockIdx.x < 288 ? blockIdx.x : blockIdx.x - 288;
    for (int i = xb * 256 + t; i < n4; i += 288 * 256) {
      float4 v = reinterpret_cast<const float4*>(in)[i];
      bf16x4 o = {(bf16)v.x, (bf16)v.y, (bf16)v.z, (bf16)v.w};
      reinterpret_cast<bf16x4*>(out)[i] = o;
    }
  } else if (y == 2) {  // Wv [H][D] -> WvT [D][H] bf16
    const int c0 = (blockIdx.x % 24) * 32, r0 = (blockIdx.x / 24) * 32;
    const int tx = t & 31, ty = t >> 5;
#pragma unroll
    for (int i = 0; i < 32; i += 8)
      shm[(ty + i) * 33 + tx] = Wv[(long)(r0 + ty + i) * HIDDEN + (c0 + tx)];
    __syncthreads();
#pragma unroll
    for (int i = 0; i < 32; i += 8)
      WvT[(long)(c0 + ty + i) * HIDDEN + (r0 + tx)] = (bf16)shm[tx * 33 + ty + i];
  } else {  // bqk[h] = sum_d bq[d]*Wk[h][d]
    if (blockIdx.x >= 192) return;
    const int h = blockIdx.x * 4 + (t >> 6);
    const int l = t & 63;
    float s = 0.0f;
#pragma unroll
    for (int d = l; d < HIDDEN; d += 64) s += bq[d] * Wk[(long)h * HIDDEN + d];
#pragma unroll
    for (int o = 32; o > 0; o >>= 1) s += __shfl_xor(s, o);
    if (l == 0) bqk[h] = s;
  }
}

// ---------------------------------------------------------------------------
// Fused: hs fp32 [B*S][H] -> hsb bf16 (same layout) + hsT fp8 e4m3 [B][H][S].
__global__ __launch_bounds__(256) void k_cvt_hs_dual(const float* __restrict__ hs,
                                                     bf16* __restrict__ hsb,
                                                     u8* __restrict__ hsT) {
  __shared__ float T[32][65];
  const int h0 = blockIdx.x * 64;
  const int s0g = blockIdx.y * 32;  // global row in [0, B*S)
  const int b = s0g >> 13;          // / 8192
  const int sIn = s0g & 8191;
  const int t = threadIdx.x;
  const int r = t >> 3, c = (t & 7) * 8;

  const float* src = hs + (long)(s0g + r) * HIDDEN + h0 + c;
  float4 v0 = *reinterpret_cast<const float4*>(src);
  float4 v1 = *reinterpret_cast<const float4*>(src + 4);
  T[r][c + 0] = v0.x; T[r][c + 1] = v0.y; T[r][c + 2] = v0.z; T[r][c + 3] = v0.w;
  T[r][c + 4] = v1.x; T[r][c + 5] = v1.y; T[r][c + 6] = v1.z; T[r][c + 7] = v1.w;

  bf16x8 o = {(bf16)v0.x, (bf16)v0.y, (bf16)v0.z, (bf16)v0.w,
              (bf16)v1.x, (bf16)v1.y, (bf16)v1.z, (bf16)v1.w};
  *reinterpret_cast<bf16x8*>(hsb + (long)(s0g + r) * HIDDEN + h0 + c) = o;

  __syncthreads();
  const int hh = t >> 2, ss = (t & 3) * 8;
  unsigned long long v8 = 0;
#pragma unroll
  for (int k = 0; k < 8; ++k)
    v8 |= (unsigned long long)to_fp8(T[ss + k][hh]) << (8 * k);
  *reinterpret_cast<unsigned long long*>(
      hsT + ((long)b * HIDDEN + h0 + hh) * SEQ + sIn + ss) = v8;
}

// ---------------------------------------------------------------------------
// Small-GEMM workhorse (round-7/13 verified): 128x128, BK=32, counted vmcnt(4),
// K-loop LDS swizzle, group-swizzled bf16 bounce epilogue / direct fp32 stores.
template <typename OUT>
__global__ __launch_bounds__(256) void k_gemm_bt(
    const bf16* __restrict__ A, const bf16* __restrict__ B, OUT* __restrict__ C,
    const float* __restrict__ bias, int N, int K, float scale,
    int nx, int ny, long strA, long strB, long strC) {
  const int id = xcd_swz();
  const int col = id % nx;
  const int row = (id / nx) % ny;
  const int z = id / (nx * ny);

  __shared__ bf16 smem[16384];

  const int tid = threadIdx.x;
  const int lane = tid & 63, wave = tid >> 6;
  const int wr = wave >> 1, wc = wave & 1;
  const int lr = lane & 15, l16 = lane >> 4, lg = (lane >> 4) * 4;
  const int sl = (l16 ^ (lr & 3) ^ ((lr >> 2) & 3)) * 8;

  const bf16* At = A + (long)z * strA + (long)row * 128 * K;
  const bf16* Bt = B + (long)z * strB + (long)col * 128 * K;

#define STAGE_TILE(buf, k0)                                                   \
  {                                                                           \
    bf16* dA = smem + (buf) * 4096;                                           \
    bf16* dB = smem + 8192 + (buf) * 4096;                                    \
    _Pragma("unroll") for (int h = 0; h < 2; ++h) {                           \
      const int cch = tid + h * 256;                                          \
      const int rr = cch >> 2;                                                \
      const int src = ((cch & 3) ^ (rr & 3) ^ ((rr >> 2) & 3)) * 8;           \
      GLOAD16(At + (long)rr * K + (k0) + src, (char*)dA + cch * 16);          \
      GLOAD16(Bt + (long)rr * K + (k0) + src, (char*)dB + cch * 16);          \
    }                                                                         \
  }

  STAGE_TILE(0, 0);

  f32x4 acc[4][4] = {};
  const int nt = K / 32;
  int cur = 0;
#pragma unroll 1
  for (int t = 0; t < nt; ++t) {
    FENCE;
    __builtin_amdgcn_s_barrier();
    FENCE;
    if (t + 1 < nt) {
      STAGE_TILE(cur ^ 1, (t + 1) * 32);
      asm volatile("s_waitcnt vmcnt(4)" ::: "memory");
    } else {
      asm volatile("s_waitcnt vmcnt(0)" ::: "memory");
    }
    __builtin_amdgcn_s_barrier();
    FENCE;
    const bf16* rA = smem + cur * 4096;
    const bf16* rB = smem + 8192 + cur * 4096;
    bf16x8 af[4], bfr[4];
#pragma unroll
    for (int m = 0; m < 4; ++m)
      af[m] = *reinterpret_cast<const bf16x8*>(&rA[(wr * 64 + m * 16 + lr) * 32 + sl]);
#pragma unroll
    for (int n = 0; n < 4; ++n)
      bfr[n] = *reinterpret_cast<const bf16x8*>(&rB[(wc * 64 + n * 16 + lr) * 32 + sl]);
    __builtin_amdgcn_s_setprio(1);
#pragma unroll
    for (int m = 0; m < 4; ++m)
#pragma unroll
      for (int n = 0; n < 4; ++n)
        acc[m][n] = MFMA_BF16(af[m], bfr[n], acc[m][n], 0, 0, 0);
    __builtin_amdgcn_s_setprio(0);
    cur ^= 1;
  }
#undef STAGE_TILE

  if constexpr (__is_same(OUT, float)) {
    float* Cb = (float*)C + (long)z * strC;
#pragma unroll
    for (int m = 0; m < 4; ++m)
#pragma unroll
      for (int n = 0; n < 4; ++n) {
        const int gc = col * 128 + wc * 64 + n * 16 + lr;
        const float bv = bias ? bias[gc] : 0.0f;
#pragma unroll
        for (int j = 0; j < 4; ++j) {
          const int gr = row * 128 + wr * 64 + m * 16 + lg + j;
          Cb[(long)gr * N + gc] = acc[m][n][j] * scale + bv;
        }
      }
  } else {
    FENCE;
    __builtin_amdgcn_s_barrier();
    FENCE;
#pragma unroll
    for (int m = 0; m < 4; ++m)
#pragma unroll
      for (int n = 0; n < 4; ++n) {
        const int gc = col * 128 + wc * 64 + n * 16 + lr;
        const float bv = bias ? bias[gc] : 0.0f;
#pragma unroll
        for (int j = 0; j < 4; ++j) {
          const int prow = wr * 64 + m * 16 + lg + j;
          const int pcol = (wc * 64 + n * 16 + lr) ^ (l16 << 4);
          smem[prow * 128 + pcol] = (bf16)(acc[m][n][j] * scale + bv);
        }
      }
    __syncthreads();
    OUT* Cb = C + (long)z * strC;
    const long rb = (long)row * 128, cb = (long)col * 128;
#pragma unroll
    for (int i = 0; i < 8; ++i) {
      const int ch = tid + i * 256;
      const int rr = ch >> 4;
      const int ce = (ch & 15) * 8;
      const int lcol = ce ^ (((rr >> 2) & 3) << 4);
      *reinterpret_cast<bf16x8*>(&Cb[(rb + rr) * N + cb + lcol]) =
          *reinterpret_cast<const bf16x8*>(smem + ch * 8);
    }
  }
}

// ---------------------------------------------------------------------------
// SCORES 256x256, BK=64, 8 waves (2M x 4N), LDS 128KB double-buffered.
// (r15-verified: 0 bank conflicts, 76.8 us. (512,2) is REQUIRED — (512,4)
// caps VGPR at 128 and spills acc[8][4] to scratch: r16 was 5.4x slower.)
// K-loop: {barrier | stage FULL next tile (8 loads/thread) | vmcnt(8):
// 16 outstanding -> oldest 8 (tile t) resident, t+1 in flight | barrier |
// 64 MFMA}. Swizzle: rows = 128B = 8 chunks; physical chunk = logical ^
// (row&7), inverse on gload SOURCE (dest linear); read key (ks*4+l16)^(lr&7).
__global__ __launch_bounds__(512, 2) void k_score256(
    const bf16* __restrict__ A, const bf16* __restrict__ B, u8* __restrict__ Pr,
    const float* __restrict__ mask, float* __restrict__ rspart, float scale) {
  __shared__ char smem[131072];
  const int tid = threadIdx.x;
  const int lane = tid & 63, wave = tid >> 6;
  const int wm = wave >> 2, wn = wave & 3;   // 2M x 4N wave grid
  const int lr = lane & 15, l16 = lane >> 4;

  const int id = xcd_swz();                  // 512 = 4 rows x 32 cols x 4 z
  const int row = id & 3;
  const int col = (id >> 2) & 31;
  const int z = id >> 7;
  const bf16* Ap = A + ((long)z * NQ + row * 256) * HIDDEN;
  const bf16* Bp = B + ((long)z * SEQ + col * 256) * HIDDEN;

  const int off0 = (l16 ^ (lr & 7)) * 16;        // ks=0 chunk byte-offset
  const int off1 = ((4 + l16) ^ (lr & 7)) * 16;  // ks=1

  // stage the full 256x64 A and B tiles for one K-step (8 loads/thread)
  auto STG_ALL = [&](int buf, int k0) {
    char* dA = smem + buf * 32768;
    char* dB = smem + 65536 + buf * 32768;
#pragma unroll
    for (int h = 0; h < 4; ++h) {
      const int c = tid + h * 512;            // 2048 chunks of 16B each
      const int r = c >> 3;                   // row 0..255
      const int l = (c & 7) ^ (r & 7);        // logical chunk for dest chunk c&7
      GLOAD16(Ap + (long)r * HIDDEN + k0 + l * 8, dA + c * 16);
      GLOAD16(Bp + (long)r * HIDDEN + k0 + l * 8, dB + c * 16);
    }
  };

  f32x4 acc[8][4] = {};
  const int NT = HIDDEN / 64;  // 12
  STG_ALL(0, 0);

#pragma unroll 1
  for (int t = 0; t < NT; ++t) {
    FENCE;
    __builtin_amdgcn_s_barrier();  // reads of tile t-1 done -> its buffer free
    FENCE;
    if (t + 1 < NT) {
      STG_ALL((t + 1) & 1, (t + 1) * 64);
      asm volatile("s_waitcnt vmcnt(8)" ::: "memory");  // tile t fully resident
    } else {
      asm volatile("s_waitcnt vmcnt(0)" ::: "memory");
    }
    __builtin_amdgcn_s_barrier();  // every thread sees tile t
    FENCE;
    const char* sA = smem + (t & 1) * 32768;
    const char* sB = smem + 65536 + (t & 1) * 32768;
    bf16x8 af[4], bfv[4];
#pragma unroll
    for (int ks = 0; ks < 2; ++ks) {
      const int off = ks ? off1 : off0;
#pragma unroll
      for (int n = 0; n < 4; ++n)
        bfv[n] = *reinterpret_cast<const bf16x8*>(
            sB + (wn * 64 + n * 16 + lr) * 128 + off);
#pragma unroll
      for (int mh = 0; mh < 2; ++mh) {
#pragma unroll
        for (int m = 0; m < 4; ++m)
          af[m] = *reinterpret_cast<const bf16x8*>(
              sA + (wm * 128 + mh * 64 + m * 16 + lr) * 128 + off);
        __builtin_amdgcn_s_setprio(1);
#pragma unroll
        for (int m = 0; m < 4; ++m)
#pragma unroll
          for (int n = 0; n < 4; ++n)
            acc[mh * 4 + m][n] = MFMA_BF16(af[m], bfv[n], acc[mh * 4 + m][n], 0, 0, 0);
        __builtin_amdgcn_s_setprio(0);
      }
    }
  }

  // ---- epilogue: exp2 + fp8, rowsum partials, group-swizzled LDS bounce ----
  __syncthreads();  // all compute reads of smem done before reuse as C tile
  u8* sm8 = (u8*)smem;
  const float sL = scale * L2E;
  float mb[4];
#pragma unroll
  for (int n = 0; n < 4; ++n) {
    const int gc = col * 256 + wn * 64 + n * 16 + lr;
    mb[n] = (1.0f - mask[(long)z * SEQ + gc]) * (-10000.0f * L2E);
  }
  float rsv[8][4];
#pragma unroll
  for (int m = 0; m < 8; ++m)
#pragma unroll
    for (int j = 0; j < 4; ++j) rsv[m][j] = 0.0f;
#pragma unroll
  for (int m = 0; m < 8; ++m)
#pragma unroll
    for (int n = 0; n < 4; ++n)
#pragma unroll
      for (int j = 0; j < 4; ++j) {
        const float v = EXP2(fmaf(acc[m][n][j], sL, mb[n]));
        rsv[m][j] += v;
        const int prow = wm * 128 + m * 16 + l16 * 4 + j;
        const int pcol = (wn * 64 + n * 16 + lr) ^ (l16 << 5);
        sm8[prow * 256 + pcol] = to_fp8(v);
      }
#pragma unroll
  for (int m = 0; m < 8; ++m)
#pragma unroll
    for (int j = 0; j < 4; ++j) {
      float v = rsv[m][j];
      v += __shfl_xor(v, 1); v += __shfl_xor(v, 2);
      v += __shfl_xor(v, 4); v += __shfl_xor(v, 8);
      if (lr == 0) {
        const int gr = row * 256 + wm * 128 + m * 16 + l16 * 4 + j;
        rspart[((long)z * NQ + gr) * 128 + col * 4 + wn] = v;
      }
    }
  __syncthreads();
  u8* Cb = Pr + ((long)z * NQ + row * 256) * SEQ + (long)col * 256;
#pragma unroll
  for (int i = 0; i < 8; ++i) {
    const int ch = tid + i * 512;   // 4096 chunks of 16B = 256x256 u8
    const int rr = ch >> 4;
    const int ce = (ch & 15) * 16;
    const int lcol = ce ^ (((rr >> 2) & 3) << 5);
    *reinterpret_cast<u32x4*>(&Cb[(long)rr * SEQ + lcol]) =
        *reinterpret_cast<const u32x4*>(sm8 + ch * 16);
  }
}

// rowsum[row] = sum of 128 partial slots (deterministic reduce)
__global__ __launch_bounds__(256) void k_rowsum(const float* __restrict__ rp,
                                                float* __restrict__ rs) {
  const int t = threadIdx.x;
  const int row = blockIdx.x * 8 + (t >> 5);
  const int s = t & 31;
  const float* base = rp + (long)row * 128;
  float v = base[s] + base[s + 32] + base[s + 64] + base[s + 96];
  v += __shfl_xor(v, 1); v += __shfl_xor(v, 2); v += __shfl_xor(v, 4);
  v += __shfl_xor(v, 8); v += __shfl_xor(v, 16);
  if (s == 0) rs[row] = v;
}

// ---------------------------------------------------------------------------
// PHS split-K partial GEMM (FP8): Cpart[kc][b,q,:] = P8[b,q-tile,kc] . hsT8^T
// 128x128 tile, BK=32, mfma_f32_16x16x32_fp8_fp8; counted vmcnt(2).
__global__ __launch_bounds__(256) void k_gemm_phs(const u8* __restrict__ P,
                                                  const u8* __restrict__ HT,
                                                  bf16* __restrict__ Cp) {
  const int id = xcd_swz();
  const int col = id % 6;
  int r = id / 6;
  const int row = r % 8;
  r /= 8;
  const int b = r % 4;
  const int kc = r / 4;

  __shared__ char smem[32768];
  u8* sm8 = (u8*)smem;

  const int tid = threadIdx.x;
  const int lane = tid & 63, wave = tid >> 6;
  const int wr = wave >> 1, wc = wave & 1;
  const int lr = lane & 15, l16 = lane >> 4;
  const int lg = l16 * 4;
  const int ps = (((l16 >> 1) ^ ((lr >> 2) & 1)) * 16) + (l16 & 1) * 8;

  const u8* At = P + (long)b * NQ * SEQ + (long)row * 128 * SEQ + (long)kc * PHS_KC;
  const u8* Bt = HT + ((long)b * HIDDEN + (long)col * 128) * SEQ + (long)kc * PHS_KC;

#define STAGE_P8(buf, k0)                                                     \
  {                                                                           \
    u8* dA = sm8 + (buf) * 4096;                                              \
    u8* dB = sm8 + 8192 + (buf) * 4096;                                       \
    const int rr = tid >> 1;                                                  \
    const int src = ((tid & 1) ^ ((rr >> 2) & 1)) * 16;                       \
    GLOAD16(At + (long)rr * SEQ + (k0) + src, dA + tid * 16);                 \
    GLOAD16(Bt + (long)rr * SEQ + (k0) + src, dB + tid * 16);                 \
  }

  const int nt = PHS_KC / 32;  // 64
  STAGE_P8(0, 0);

  f32x4 acc[4][4] = {};
#pragma unroll 1
  for (int t = 0; t < nt; ++t) {
    FENCE;
    __builtin_amdgcn_s_barrier();
    FENCE;
    if (t + 1 < nt) {
      STAGE_P8((t + 1) & 1, (t + 1) * 32);
      asm volatile("s_waitcnt vmcnt(2)" ::: "memory");
    } else {
      asm volatile("s_waitcnt vmcnt(0)" ::: "memory");
    }
    __builtin_amdgcn_s_barrier();
    FENCE;
    const u8* rA = sm8 + (t & 1) * 4096;
    const u8* rB = sm8 + 8192 + (t & 1) * 4096;
    long af[4], bfr[4];
#pragma unroll
    for (int m = 0; m < 4; ++m)
      af[m] = *reinterpret_cast<const long*>(rA + (wr * 64 + m * 16 + lr) * 32 + ps);
#pragma unroll
    for (int n = 0; n < 4; ++n)
      bfr[n] = *reinterpret_cast<const long*>(rB + (wc * 64 + n * 16 + lr) * 32 + ps);
    __builtin_amdgcn_s_setprio(1);
#pragma unroll
    for (int m = 0; m < 4; ++m)
#pragma unroll
      for (int n = 0; n < 4; ++n)
        acc[m][n] = __builtin_amdgcn_mfma_f32_16x16x32_fp8_fp8(af[m], bfr[n], acc[m][n], 0, 0, 0);
    __builtin_amdgcn_s_setprio(0);
  }
#undef STAGE_P8

  FENCE;
  __builtin_amdgcn_s_barrier();
  FENCE;
  bf16* smb = (bf16*)smem;
#pragma unroll
  for (int m = 0; m < 4; ++m)
#pragma unroll
    for (int n = 0; n < 4; ++n)
#pragma unroll
      for (int j = 0; j < 4; ++j) {
        const int prow = wr * 64 + m * 16 + lg + j;
        const int pcol = (wc * 64 + n * 16 + lr) ^ (l16 << 4);
        smb[prow * 128 + pcol] = (bf16)acc[m][n][j];
      }
  __syncthreads();
  bf16* Co = Cp + ((long)kc * BATCH + b) * NQ * HIDDEN;
  const long rb = (long)row * 128, cb = (long)col * 128;
#pragma unroll
  for (int i = 0; i < 8; ++i) {
    const int ch = tid + i * 256;
    const int rr = ch >> 4;
    const int ce = (ch & 15) * 8;
    const int lcol = ce ^ (((rr >> 2) & 3) << 4);
    *reinterpret_cast<bf16x8*>(&Co[(rb + rr) * HIDDEN + cb + lcol]) =
        *reinterpret_cast<const bf16x8*>(smb + ch * 8);
  }
}

// ---------------------------------------------------------------------------
// V-fold with inline partial-reduce + normalize:
// out[q,:] = ((sum_kc Ppart[kc][q,:]) / rowsum[q]) . Wv + bv
__global__ __launch_bounds__(256) void k_vfold(const bf16* __restrict__ Pp,
                                               const float* __restrict__ rs,
                                               const bf16* __restrict__ WvT,
                                               const float* __restrict__ bias,
                                               float* __restrict__ out) {
  const int id = xcd_swz();
  const int col = id % 6;
  const int row = id / 6;

  __shared__ bf16 smem[16384];

  const int tid = threadIdx.x;
  const int lane = tid & 63, wave = tid >> 6;
  const int wr = wave >> 1, wc = wave & 1;
  const int lr = lane & 15, l16 = lane >> 4, lg = (lane >> 4) * 4;
  const int sl = (l16 ^ (lr & 3) ^ ((lr >> 2) & 3)) * 8;

  const long NB = (long)BATCH * NQ * HIDDEN;
  const bf16* At = Pp + (long)row * 128 * HIDDEN;
  const bf16* Bt = WvT + (long)col * 128 * HIDDEN;
  const float inv0 = 1.0f / rs[row * 128 + (tid >> 2)];
  const float inv1 = 1.0f / rs[row * 128 + 64 + (tid >> 2)];

  auto STAGE = [&](int buf, int k0) {
    bf16* dA = smem + buf * 4096;
    bf16* dB = smem + 8192 + buf * 4096;
#pragma unroll
    for (int h = 0; h < 2; ++h) {
      const int c = tid + h * 256;
      const int rr = c >> 2;
      const int swz = ((c & 3) ^ (rr & 3) ^ ((rr >> 2) & 3)) * 8;
      const int cc = (c & 3) * 8;
      float s8[8] = {};
#pragma unroll
      for (int kc = 0; kc < PHS_KS; ++kc) {
        bf16x8 v = *reinterpret_cast<const bf16x8*>(
            At + (long)kc * NB + (long)rr * HIDDEN + k0 + cc);
#pragma unroll
        for (int j = 0; j < 8; ++j) s8[j] += (float)v[j];
      }
      const float inv = h ? inv1 : inv0;
      bf16x8 o;
#pragma unroll
      for (int j = 0; j < 8; ++j) o[j] = (bf16)(s8[j] * inv);
      *reinterpret_cast<bf16x8*>(dA + rr * 32 + swz) = o;
      GLOAD16(Bt + (long)rr * HIDDEN + k0 + swz, (char*)dB + c * 16);
    }
  };

  const int nt = HIDDEN / 32;  // 24
  STAGE(0, 0);
  __syncthreads();

  f32x4 acc[4][4] = {};
  int cur = 0;
#pragma unroll 1
  for (int t = 0; t < nt; ++t) {
    if (t + 1 < nt) STAGE(cur ^ 1, (t + 1) * 32);
    const bf16* rA = smem + cur * 4096;
    const bf16* rB = smem + 8192 + cur * 4096;
    bf16x8 af[4], bfr[4];
#pragma unroll
    for (int m = 0; m < 4; ++m)
      af[m] = *reinterpret_cast<const bf16x8*>(&rA[(wr * 64 + m * 16 + lr) * 32 + sl]);
#pragma unroll
    for (int n = 0; n < 4; ++n)
      bfr[n] = *reinterpret_cast<const bf16x8*>(&rB[(wc * 64 + n * 16 + lr) * 32 + sl]);
#pragma unroll
    for (int m = 0; m < 4; ++m)
#pragma unroll
      for (int n = 0; n < 4; ++n)
        acc[m][n] = MFMA_BF16(af[m], bfr[n], acc[m][n], 0, 0, 0);
    __syncthreads();
    cur ^= 1;
  }

#pragma unroll
  for (int m = 0; m < 4; ++m)
#pragma unroll
    for (int n = 0; n < 4; ++n) {
      const int gc = col * 128 + wc * 64 + n * 16 + lr;
      const float bv = bias[gc];
#pragma unroll
      for (int j = 0; j < 4; ++j) {
        const int gr = row * 128 + wr * 64 + m * 16 + lg + j;
        out[(long)gr * HIDDEN + gc] = acc[m][n][j] + bv;
      }
    }
}

// ---------------------------------------------------------------------------
extern "C" void kernel_launch(void* const* d_in, const int* in_sizes, int n_in,
                              void* d_out, int out_size, void* d_ws, size_t ws_size,
                              hipStream_t stream) {
  const float* hs = (const float*)d_in[0];    // [B,S,H]
  const float* qu = (const float*)d_in[1];    // [B,Q,H]
  const float* mask = (const float*)d_in[2];  // [B,S]
  const float* Wq = (const float*)d_in[3];
  const float* bq = (const float*)d_in[4];
  const float* Wk = (const float*)d_in[5];
  const float* Wv = (const float*)d_in[7];
  const float* bv = (const float*)d_in[8];
  float* out = (float*)d_out;  // [B,Q,H] fp32
  // bk (d_in[6]) adds a softmax-row-constant -> cancels exactly.

  const size_t HS_N = (size_t)BATCH * SEQ * HIDDEN;
  const size_t QU_N = (size_t)BATCH * NQ * HIDDEN;
  const size_t W_N = (size_t)HIDDEN * HIDDEN;
  const size_t P_N = (size_t)BATCH * NQ * SEQ;

  char* ws = (char*)d_ws;
  size_t off = 0;
  auto alloc = [&](size_t bytes) {
    char* p = ws + off;
    off += (bytes + 255) & ~(size_t)255;
    return p;
  };

  // regionA: hsb (live through scores) / PHS partials (after) — overlap
  char* regionA = alloc(HS_N * 2);
  bf16* hsb = (bf16*)regionA;
  bf16* Ppart = (bf16*)regionA;        // PHS_KS(4) * QU_N bf16 = 25.2 MB
  u8* hsT8 = (u8*)alloc(HS_N);         // [B][H][S] fp8 e4m3
  u8* Pr = (u8*)alloc(P_N);            // unnormalized probs exp(s+mb), fp8
  bf16* qub = (bf16*)alloc(QU_N * 2);
  bf16* tmpb = (bf16*)alloc(QU_N * 2); // folded query: qu.(Wq.Wk^T) + bq.Wk^T
  bf16* Wkb = (bf16*)alloc(W_N * 2);
  bf16* Wqb = (bf16*)alloc(W_N * 2);
  bf16* WvT = (bf16*)alloc(W_N * 2);
  bf16* Mt = (bf16*)alloc(W_N * 2);    // Wk.Wq^T
  float* bqk = (float*)alloc(HIDDEN * 4);
  float* rspart = (float*)alloc((size_t)BATCH * NQ * 128 * 4);  // 2 MB
  float* rowsum = (float*)alloc((size_t)BATCH * NQ * 4);

  // 1) fused prep (qu cvt, Wk/Wq cvt, Wv transpose, bqk gemv) + hs prep
  k_prep<<<dim3(576, 4), dim3(256), 0, stream>>>(qu, qub, Wk, Wkb, Wq, Wqb,
                                                 Wv, WvT, bq, bqk);
  k_cvt_hs_dual<<<dim3(12, 1024), dim3(256), 0, stream>>>(hs, hsb, hsT8);

  // 2) Mt = Wk.Wq^T  [768x768]
  k_gemm_bt<bf16><<<dim3(36), dim3(256), 0, stream>>>(
      Wkb, Wqb, Mt, nullptr, HIDDEN, HIDDEN, 1.0f, 6, 6, 0, 0, 0);

  // 3) folded query: tmp = qub.Mt^T + bqk  [4096x768]
  k_gemm_bt<bf16><<<dim3(192), dim3(256), 0, stream>>>(
      qub, Mt, tmpb, bqk, HIDDEN, HIDDEN, 1.0f, 6, 32, 0, 0, 0);

  // 4) scores (256x256, BK=64, r15-verified): Pr(fp8) = exp2(...), rowsum partials
  const float qkscale = 1.0f / sqrtf((float)HIDDEN);
  k_score256<<<dim3(512), dim3(512), 0, stream>>>(tmpb, hsb, Pr, mask, rspart, qkscale);
  k_rowsum<<<dim3(BATCH * NQ / 8), dim3(256), 0, stream>>>(rspart, rowsum);

  // 5) PHS partials (fp8 MFMA): Ppart[kc] = P8[:, kc-chunk] . hsT8^T
  k_gemm_phs<<<dim3(6 * 8 * 4 * PHS_KS), dim3(256), 0, stream>>>(Pr, hsT8, Ppart);

  // 6) V-fold with inline reduce+normalize: out = ((sum Ppart)/rowsum).Wv + bv
  k_vfold<<<dim3(192), dim3(256), 0, stream>>>(Ppart, rowsum, WvT, bv, out);
}

// Round 18
// 222.375 us; speedup vs baseline: 2.5060x; 1.0355x over previous
//
#include <hip/hip_runtime.h>
#include <hip/hip_bf16.h>
#include <hip/hip_fp8.h>
#include <stdint.h>
#include <math.h>

#define HIDDEN 768
#define BATCH 4
#define SEQ 8192
#define NQ 1024
#define PHS_KS 4
#define PHS_KC (SEQ / PHS_KS)

typedef __bf16 bf16;
typedef unsigned char u8;
typedef __bf16 bf16x4 __attribute__((ext_vector_type(4)));
typedef __bf16 bf16x8 __attribute__((ext_vector_type(8)));
typedef float f32x4 __attribute__((ext_vector_type(4)));
typedef unsigned int u32x4 __attribute__((ext_vector_type(4)));

#define L2E 1.44269504088896f

#if __has_builtin(__builtin_amdgcn_exp2f)
#define EXP2(x) __builtin_amdgcn_exp2f(x)
#else
#define EXP2(x) exp2f(x)
#endif

__device__ inline u8 to_fp8(float v) {
  return (u8)__hip_cvt_float_to_fp8(v, __HIP_SATFINITE, __HIP_E4M3);
}

// General bijective XCD-chunked block-id swizzle (m204 formula, any grid size).
__device__ inline int xcd_swz() {
  const unsigned n = gridDim.x, o = blockIdx.x;
  const unsigned q = n >> 3, r = n & 7;
  const unsigned x = o & 7, k = o >> 3;
  return (int)((x < r ? x * (q + 1) : r * (q + 1) + (x - r) * q) + k);
}

#define GLOAD16(gptr, lptr)                                                   \
  __builtin_amdgcn_global_load_lds(                                           \
      (const __attribute__((address_space(1))) void*)(gptr),                  \
      (__attribute__((address_space(3))) void*)(lptr), 16, 0, 0)

#define FENCE asm volatile("" ::: "memory")
#define MFMA_BF16 __builtin_amdgcn_mfma_f32_16x16x32_bf16

// ---------------------------------------------------------------------------
// Fused prep: y=0 qu cvt, y=1 Wk+Wq cvt, y=2 Wv transpose-cvt, y=3 bqk gemv.
__global__ __launch_bounds__(256) void k_prep(
    const float* __restrict__ qu, bf16* __restrict__ qub,
    const float* __restrict__ Wk, bf16* __restrict__ Wkb,
    const float* __restrict__ Wq, bf16* __restrict__ Wqb,
    const float* __restrict__ Wv, bf16* __restrict__ WvT,
    const float* __restrict__ bq, float* __restrict__ bqk) {
  __shared__ float shm[32 * 33];
  const int t = threadIdx.x;
  const int y = blockIdx.y;

  if (y == 0) {  // qu fp32 -> bf16
    const int n4 = (int)((size_t)BATCH * NQ * HIDDEN / 4);
    const int stride = gridDim.x * 256;
    for (int i = blockIdx.x * 256 + t; i < n4; i += stride) {
      float4 v = reinterpret_cast<const float4*>(qu)[i];
      bf16x4 o = {(bf16)v.x, (bf16)v.y, (bf16)v.z, (bf16)v.w};
      reinterpret_cast<bf16x4*>(qub)[i] = o;
    }
  } else if (y == 1) {  // Wk (x<288) / Wq (x>=288) cvt
    const int n4 = HIDDEN * HIDDEN / 4;
    const float* in = blockIdx.x < 288 ? Wk : Wq;
    bf16* out = blockIdx.x < 288 ? Wkb : Wqb;
    const int xb = blockIdx.x < 288 ? blockIdx.x : blockIdx.x - 288;
    for (int i = xb * 256 + t; i < n4; i += 288 * 256) {
      float4 v = reinterpret_cast<const float4*>(in)[i];
      bf16x4 o = {(bf16)v.x, (bf16)v.y, (bf16)v.z, (bf16)v.w};
      reinterpret_cast<bf16x4*>(out)[i] = o;
    }
  } else if (y == 2) {  // Wv [H][D] -> WvT [D][H] bf16
    const int c0 = (blockIdx.x % 24) * 32, r0 = (blockIdx.x / 24) * 32;
    const int tx = t & 31, ty = t >> 5;
#pragma unroll
    for (int i = 0; i < 32; i += 8)
      shm[(ty + i) * 33 + tx] = Wv[(long)(r0 + ty + i) * HIDDEN + (c0 + tx)];
    __syncthreads();
#pragma unroll
    for (int i = 0; i < 32; i += 8)
      WvT[(long)(c0 + ty + i) * HIDDEN + (r0 + tx)] = (bf16)shm[tx * 33 + ty + i];
  } else {  // bqk[h] = sum_d bq[d]*Wk[h][d]
    if (blockIdx.x >= 192) return;
    const int h = blockIdx.x * 4 + (t >> 6);
    const int l = t & 63;
    float s = 0.0f;
#pragma unroll
    for (int d = l; d < HIDDEN; d += 64) s += bq[d] * Wk[(long)h * HIDDEN + d];
#pragma unroll
    for (int o = 32; o > 0; o >>= 1) s += __shfl_xor(s, o);
    if (l == 0) bqk[h] = s;
  }
}

// ---------------------------------------------------------------------------
// Fused: hs fp32 [B*S][H] -> hsb bf16 (same layout) + hsT fp8 e4m3 [B][H][S].
__global__ __launch_bounds__(256) void k_cvt_hs_dual(const float* __restrict__ hs,
                                                     bf16* __restrict__ hsb,
                                                     u8* __restrict__ hsT) {
  __shared__ float T[32][65];
  const int h0 = blockIdx.x * 64;
  const int s0g = blockIdx.y * 32;  // global row in [0, B*S)
  const int b = s0g >> 13;          // / 8192
  const int sIn = s0g & 8191;
  const int t = threadIdx.x;
  const int r = t >> 3, c = (t & 7) * 8;

  const float* src = hs + (long)(s0g + r) * HIDDEN + h0 + c;
  float4 v0 = *reinterpret_cast<const float4*>(src);
  float4 v1 = *reinterpret_cast<const float4*>(src + 4);
  T[r][c + 0] = v0.x; T[r][c + 1] = v0.y; T[r][c + 2] = v0.z; T[r][c + 3] = v0.w;
  T[r][c + 4] = v1.x; T[r][c + 5] = v1.y; T[r][c + 6] = v1.z; T[r][c + 7] = v1.w;

  bf16x8 o = {(bf16)v0.x, (bf16)v0.y, (bf16)v0.z, (bf16)v0.w,
              (bf16)v1.x, (bf16)v1.y, (bf16)v1.z, (bf16)v1.w};
  *reinterpret_cast<bf16x8*>(hsb + (long)(s0g + r) * HIDDEN + h0 + c) = o;

  __syncthreads();
  const int hh = t >> 2, ss = (t & 3) * 8;
  unsigned long long v8 = 0;
#pragma unroll
  for (int k = 0; k < 8; ++k)
    v8 |= (unsigned long long)to_fp8(T[ss + k][hh]) << (8 * k);
  *reinterpret_cast<unsigned long long*>(
      hsT + ((long)b * HIDDEN + h0 + hh) * SEQ + sIn + ss) = v8;
}

// ---------------------------------------------------------------------------
// Small-GEMM workhorse (round-7/13 verified): 128x128, BK=32, counted vmcnt(4),
// K-loop LDS swizzle, group-swizzled bf16 bounce epilogue / direct fp32 stores.
template <typename OUT>
__global__ __launch_bounds__(256) void k_gemm_bt(
    const bf16* __restrict__ A, const bf16* __restrict__ B, OUT* __restrict__ C,
    const float* __restrict__ bias, int N, int K, float scale,
    int nx, int ny, long strA, long strB, long strC) {
  const int id = xcd_swz();
  const int col = id % nx;
  const int row = (id / nx) % ny;
  const int z = id / (nx * ny);

  __shared__ bf16 smem[16384];

  const int tid = threadIdx.x;
  const int lane = tid & 63, wave = tid >> 6;
  const int wr = wave >> 1, wc = wave & 1;
  const int lr = lane & 15, l16 = lane >> 4, lg = (lane >> 4) * 4;
  const int sl = (l16 ^ (lr & 3) ^ ((lr >> 2) & 3)) * 8;

  const bf16* At = A + (long)z * strA + (long)row * 128 * K;
  const bf16* Bt = B + (long)z * strB + (long)col * 128 * K;

#define STAGE_TILE(buf, k0)                                                   \
  {                                                                           \
    bf16* dA = smem + (buf) * 4096;                                           \
    bf16* dB = smem + 8192 + (buf) * 4096;                                    \
    _Pragma("unroll") for (int h = 0; h < 2; ++h) {                           \
      const int cch = tid + h * 256;                                          \
      const int rr = cch >> 2;                                                \
      const int src = ((cch & 3) ^ (rr & 3) ^ ((rr >> 2) & 3)) * 8;           \
      GLOAD16(At + (long)rr * K + (k0) + src, (char*)dA + cch * 16);          \
      GLOAD16(Bt + (long)rr * K + (k0) + src, (char*)dB + cch * 16);          \
    }                                                                         \
  }

  STAGE_TILE(0, 0);

  f32x4 acc[4][4] = {};
  const int nt = K / 32;
  int cur = 0;
#pragma unroll 1
  for (int t = 0; t < nt; ++t) {
    FENCE;
    __builtin_amdgcn_s_barrier();
    FENCE;
    if (t + 1 < nt) {
      STAGE_TILE(cur ^ 1, (t + 1) * 32);
      asm volatile("s_waitcnt vmcnt(4)" ::: "memory");
    } else {
      asm volatile("s_waitcnt vmcnt(0)" ::: "memory");
    }
    __builtin_amdgcn_s_barrier();
    FENCE;
    const bf16* rA = smem + cur * 4096;
    const bf16* rB = smem + 8192 + cur * 4096;
    bf16x8 af[4], bfr[4];
#pragma unroll
    for (int m = 0; m < 4; ++m)
      af[m] = *reinterpret_cast<const bf16x8*>(&rA[(wr * 64 + m * 16 + lr) * 32 + sl]);
#pragma unroll
    for (int n = 0; n < 4; ++n)
      bfr[n] = *reinterpret_cast<const bf16x8*>(&rB[(wc * 64 + n * 16 + lr) * 32 + sl]);
    __builtin_amdgcn_s_setprio(1);
#pragma unroll
    for (int m = 0; m < 4; ++m)
#pragma unroll
      for (int n = 0; n < 4; ++n)
        acc[m][n] = MFMA_BF16(af[m], bfr[n], acc[m][n], 0, 0, 0);
    __builtin_amdgcn_s_setprio(0);
    cur ^= 1;
  }
#undef STAGE_TILE

  if constexpr (__is_same(OUT, float)) {
    float* Cb = (float*)C + (long)z * strC;
#pragma unroll
    for (int m = 0; m < 4; ++m)
#pragma unroll
      for (int n = 0; n < 4; ++n) {
        const int gc = col * 128 + wc * 64 + n * 16 + lr;
        const float bv = bias ? bias[gc] : 0.0f;
#pragma unroll
        for (int j = 0; j < 4; ++j) {
          const int gr = row * 128 + wr * 64 + m * 16 + lg + j;
          Cb[(long)gr * N + gc] = acc[m][n][j] * scale + bv;
        }
      }
  } else {
    FENCE;
    __builtin_amdgcn_s_barrier();
    FENCE;
#pragma unroll
    for (int m = 0; m < 4; ++m)
#pragma unroll
      for (int n = 0; n < 4; ++n) {
        const int gc = col * 128 + wc * 64 + n * 16 + lr;
        const float bv = bias ? bias[gc] : 0.0f;
#pragma unroll
        for (int j = 0; j < 4; ++j) {
          const int prow = wr * 64 + m * 16 + lg + j;
          const int pcol = (wc * 64 + n * 16 + lr) ^ (l16 << 4);
          smem[prow * 128 + pcol] = (bf16)(acc[m][n][j] * scale + bv);
        }
      }
    __syncthreads();
    OUT* Cb = C + (long)z * strC;
    const long rb = (long)row * 128, cb = (long)col * 128;
#pragma unroll
    for (int i = 0; i < 8; ++i) {
      const int ch = tid + i * 256;
      const int rr = ch >> 4;
      const int ce = (ch & 15) * 8;
      const int lcol = ce ^ (((rr >> 2) & 3) << 4);
      *reinterpret_cast<bf16x8*>(&Cb[(rb + rr) * N + cb + lcol]) =
          *reinterpret_cast<const bf16x8*>(smem + ch * 8);
    }
  }
}

// ---------------------------------------------------------------------------
// SCORES 256x128, BK=32, 8 waves (4M x 2N), LDS 48KB dbuf -> 2 blocks/CU
// (4 waves/SIMD: cross-block overlap hides barrier stalls, r7 mechanism).
// acc[4][4] = 64 VGPR/wave fits the (512,4) 128-reg cap (r16's acc[8][4]
// spilled). Sync: r7-proven {barrier | stage next tile (3 loads/thr) |
// vmcnt(3): oldest 3 = tile t resident | barrier | 16 MFMA}.
// Swizzle (r16-validated, 0 conflicts): chunk ^= (row>>1)&3 on gload source,
// read key = l16 ^ ((lr>>1)&3), dest linear.
__global__ __launch_bounds__(512, 4) void k_score256(
    const bf16* __restrict__ A, const bf16* __restrict__ B, u8* __restrict__ Pr,
    const float* __restrict__ mask, float* __restrict__ rspart, float scale) {
  __shared__ char smem[49152];  // A 2x16KB @0, B 2x8KB @32768
  const int tid = threadIdx.x;
  const int lane = tid & 63, wave = tid >> 6;
  const int wm = wave >> 1, wn = wave & 1;   // 4M x 2N wave grid
  const int lr = lane & 15, l16 = lane >> 4;

  const int id = xcd_swz();                  // 1024 = 4 rows x 64 cols x 4 z
  const int row = id & 3;
  const int col = (id >> 2) & 63;
  const int z = id >> 8;
  const bf16* Ap = A + ((long)z * NQ + row * 256) * HIDDEN;
  const bf16* Bp = B + ((long)z * SEQ + col * 128) * HIDDEN;

  const int pc = (l16 ^ ((lr >> 1) & 3)) * 16;  // physical chunk byte-offset

  // stage 256x32 A (1024 chunks) + 128x32 B (512 chunks): 3 loads/thread
  auto STG = [&](int buf, int k0) {
    char* dA = smem + buf * 16384;
    char* dB = smem + 32768 + buf * 8192;
#pragma unroll
    for (int h = 0; h < 2; ++h) {
      const int c = tid + h * 512;
      const int r = c >> 2;
      const int l = (c & 3) ^ ((r >> 1) & 3);
      GLOAD16(Ap + (long)r * HIDDEN + k0 + l * 8, dA + c * 16);
    }
    {
      const int c = tid;
      const int r = c >> 2;
      const int l = (c & 3) ^ ((r >> 1) & 3);
      GLOAD16(Bp + (long)r * HIDDEN + k0 + l * 8, dB + c * 16);
    }
  };

  f32x4 acc[4][4] = {};
  const int NT = HIDDEN / 32;  // 24
  STG(0, 0);

#pragma unroll 1
  for (int t = 0; t < NT; ++t) {
    FENCE;
    __builtin_amdgcn_s_barrier();  // reads of tile t-1 done -> its buffer free
    FENCE;
    if (t + 1 < NT) {
      STG((t + 1) & 1, (t + 1) * 32);
      asm volatile("s_waitcnt vmcnt(3)" ::: "memory");  // tile t fully resident
    } else {
      asm volatile("s_waitcnt vmcnt(0)" ::: "memory");
    }
    __builtin_amdgcn_s_barrier();  // every thread sees tile t
    FENCE;
    const char* sA = smem + (t & 1) * 16384;
    const char* sB = smem + 32768 + (t & 1) * 8192;
    bf16x8 af[4], bfv[4];
#pragma unroll
    for (int n = 0; n < 4; ++n)
      bfv[n] = *reinterpret_cast<const bf16x8*>(
          sB + (wn * 64 + n * 16 + lr) * 64 + pc);
#pragma unroll
    for (int m = 0; m < 4; ++m)
      af[m] = *reinterpret_cast<const bf16x8*>(
          sA + (wm * 64 + m * 16 + lr) * 64 + pc);
    __builtin_amdgcn_s_setprio(1);
#pragma unroll
    for (int m = 0; m < 4; ++m)
#pragma unroll
      for (int n = 0; n < 4; ++n)
        acc[m][n] = MFMA_BF16(af[m], bfv[n], acc[m][n], 0, 0, 0);
    __builtin_amdgcn_s_setprio(0);
  }

  // ---- epilogue: exp2 + fp8, rowsum partials, group-swizzled LDS bounce ----
  __syncthreads();  // all compute reads of smem done before reuse as C tile
  u8* sm8 = (u8*)smem;  // 256x128 u8 = 32KB
  const float sL = scale * L2E;
  float mb[4];
#pragma unroll
  for (int n = 0; n < 4; ++n) {
    const int gc = col * 128 + wn * 64 + n * 16 + lr;
    mb[n] = (1.0f - mask[(long)z * SEQ + gc]) * (-10000.0f * L2E);
  }
  float rsv[4][4];
#pragma unroll
  for (int m = 0; m < 4; ++m)
#pragma unroll
    for (int j = 0; j < 4; ++j) rsv[m][j] = 0.0f;
#pragma unroll
  for (int m = 0; m < 4; ++m)
#pragma unroll
    for (int n = 0; n < 4; ++n)
#pragma unroll
      for (int j = 0; j < 4; ++j) {
        const float v = EXP2(fmaf(acc[m][n][j], sL, mb[n]));
        rsv[m][j] += v;
        const int prow = wm * 64 + m * 16 + l16 * 4 + j;
        const int pcol = (wn * 64 + n * 16 + lr) ^ (l16 << 5);
        sm8[prow * 128 + pcol] = to_fp8(v);
      }
#pragma unroll
  for (int m = 0; m < 4; ++m)
#pragma unroll
    for (int j = 0; j < 4; ++j) {
      float v = rsv[m][j];
      v += __shfl_xor(v, 1); v += __shfl_xor(v, 2);
      v += __shfl_xor(v, 4); v += __shfl_xor(v, 8);
      if (lr == 0) {
        const int gr = row * 256 + wm * 64 + m * 16 + l16 * 4 + j;
        rspart[((long)z * NQ + gr) * 128 + col * 2 + wn] = v;
      }
    }
  __syncthreads();
  u8* Cb = Pr + ((long)z * NQ + row * 256) * SEQ + (long)col * 128;
#pragma unroll
  for (int i = 0; i < 4; ++i) {
    const int ch = tid + i * 512;   // 2048 chunks of 16B = 256x128 u8
    const int rr = ch >> 3;         // 8 chunks per 128-byte row
    const int ce = (ch & 7) * 16;
    const int lcol = ce ^ (((rr >> 2) & 3) << 5);
    *reinterpret_cast<u32x4*>(&Cb[(long)rr * SEQ + lcol]) =
        *reinterpret_cast<const u32x4*>(sm8 + ch * 16);
  }
}

// rowsum[row] = sum of 128 partial slots (deterministic reduce)
__global__ __launch_bounds__(256) void k_rowsum(const float* __restrict__ rp,
                                                float* __restrict__ rs) {
  const int t = threadIdx.x;
  const int row = blockIdx.x * 8 + (t >> 5);
  const int s = t & 31;
  const float* base = rp + (long)row * 128;
  float v = base[s] + base[s + 32] + base[s + 64] + base[s + 96];
  v += __shfl_xor(v, 1); v += __shfl_xor(v, 2); v += __shfl_xor(v, 4);
  v += __shfl_xor(v, 8); v += __shfl_xor(v, 16);
  if (s == 0) rs[row] = v;
}

// ---------------------------------------------------------------------------
// PHS split-K partial GEMM (FP8): Cpart[kc][b,q,:] = P8[b,q-tile,kc] . hsT8^T
// 128x128 tile, BK=32, mfma_f32_16x16x32_fp8_fp8; counted vmcnt(2).
__global__ __launch_bounds__(256) void k_gemm_phs(const u8* __restrict__ P,
                                                  const u8* __restrict__ HT,
                                                  bf16* __restrict__ Cp) {
  const int id = xcd_swz();
  const int col = id % 6;
  int r = id / 6;
  const int row = r % 8;
  r /= 8;
  const int b = r % 4;
  const int kc = r / 4;

  __shared__ char smem[32768];
  u8* sm8 = (u8*)smem;

  const int tid = threadIdx.x;
  const int lane = tid & 63, wave = tid >> 6;
  const int wr = wave >> 1, wc = wave & 1;
  const int lr = lane & 15, l16 = lane >> 4;
  const int lg = l16 * 4;
  const int ps = (((l16 >> 1) ^ ((lr >> 2) & 1)) * 16) + (l16 & 1) * 8;

  const u8* At = P + (long)b * NQ * SEQ + (long)row * 128 * SEQ + (long)kc * PHS_KC;
  const u8* Bt = HT + ((long)b * HIDDEN + (long)col * 128) * SEQ + (long)kc * PHS_KC;

#define STAGE_P8(buf, k0)                                                     \
  {                                                                           \
    u8* dA = sm8 + (buf) * 4096;                                              \
    u8* dB = sm8 + 8192 + (buf) * 4096;                                       \
    const int rr = tid >> 1;                                                  \
    const int src = ((tid & 1) ^ ((rr >> 2) & 1)) * 16;                       \
    GLOAD16(At + (long)rr * SEQ + (k0) + src, dA + tid * 16);                 \
    GLOAD16(Bt + (long)rr * SEQ + (k0) + src, dB + tid * 16);                 \
  }

  const int nt = PHS_KC / 32;  // 64
  STAGE_P8(0, 0);

  f32x4 acc[4][4] = {};
#pragma unroll 1
  for (int t = 0; t < nt; ++t) {
    FENCE;
    __builtin_amdgcn_s_barrier();
    FENCE;
    if (t + 1 < nt) {
      STAGE_P8((t + 1) & 1, (t + 1) * 32);
      asm volatile("s_waitcnt vmcnt(2)" ::: "memory");
    } else {
      asm volatile("s_waitcnt vmcnt(0)" ::: "memory");
    }
    __builtin_amdgcn_s_barrier();
    FENCE;
    const u8* rA = sm8 + (t & 1) * 4096;
    const u8* rB = sm8 + 8192 + (t & 1) * 4096;
    long af[4], bfr[4];
#pragma unroll
    for (int m = 0; m < 4; ++m)
      af[m] = *reinterpret_cast<const long*>(rA + (wr * 64 + m * 16 + lr) * 32 + ps);
#pragma unroll
    for (int n = 0; n < 4; ++n)
      bfr[n] = *reinterpret_cast<const long*>(rB + (wc * 64 + n * 16 + lr) * 32 + ps);
    __builtin_amdgcn_s_setprio(1);
#pragma unroll
    for (int m = 0; m < 4; ++m)
#pragma unroll
      for (int n = 0; n < 4; ++n)
        acc[m][n] = __builtin_amdgcn_mfma_f32_16x16x32_fp8_fp8(af[m], bfr[n], acc[m][n], 0, 0, 0);
    __builtin_amdgcn_s_setprio(0);
  }
#undef STAGE_P8

  FENCE;
  __builtin_amdgcn_s_barrier();
  FENCE;
  bf16* smb = (bf16*)smem;
#pragma unroll
  for (int m = 0; m < 4; ++m)
#pragma unroll
    for (int n = 0; n < 4; ++n)
#pragma unroll
      for (int j = 0; j < 4; ++j) {
        const int prow = wr * 64 + m * 16 + lg + j;
        const int pcol = (wc * 64 + n * 16 + lr) ^ (l16 << 4);
        smb[prow * 128 + pcol] = (bf16)acc[m][n][j];
      }
  __syncthreads();
  bf16* Co = Cp + ((long)kc * BATCH + b) * NQ * HIDDEN;
  const long rb = (long)row * 128, cb = (long)col * 128;
#pragma unroll
  for (int i = 0; i < 8; ++i) {
    const int ch = tid + i * 256;
    const int rr = ch >> 4;
    const int ce = (ch & 15) * 8;
    const int lcol = ce ^ (((rr >> 2) & 3) << 4);
    *reinterpret_cast<bf16x8*>(&Co[(rb + rr) * HIDDEN + cb + lcol]) =
        *reinterpret_cast<const bf16x8*>(smb + ch * 8);
  }
}

// ---------------------------------------------------------------------------
// V-fold with inline partial-reduce + normalize:
// out[q,:] = ((sum_kc Ppart[kc][q,:]) / rowsum[q]) . Wv + bv
__global__ __launch_bounds__(256) void k_vfold(const bf16* __restrict__ Pp,
                                               const float* __restrict__ rs,
                                               const bf16* __restrict__ WvT,
                                               const float* __restrict__ bias,
                                               float* __restrict__ out) {
  const int id = xcd_swz();
  const int col = id % 6;
  const int row = id / 6;

  __shared__ bf16 smem[16384];

  const int tid = threadIdx.x;
  const int lane = tid & 63, wave = tid >> 6;
  const int wr = wave >> 1, wc = wave & 1;
  const int lr = lane & 15, l16 = lane >> 4, lg = (lane >> 4) * 4;
  const int sl = (l16 ^ (lr & 3) ^ ((lr >> 2) & 3)) * 8;

  const long NB = (long)BATCH * NQ * HIDDEN;
  const bf16* At = Pp + (long)row * 128 * HIDDEN;
  const bf16* Bt = WvT + (long)col * 128 * HIDDEN;
  const float inv0 = 1.0f / rs[row * 128 + (tid >> 2)];
  const float inv1 = 1.0f / rs[row * 128 + 64 + (tid >> 2)];

  auto STAGE = [&](int buf, int k0) {
    bf16* dA = smem + buf * 4096;
    bf16* dB = smem + 8192 + buf * 4096;
#pragma unroll
    for (int h = 0; h < 2; ++h) {
      const int c = tid + h * 256;
      const int rr = c >> 2;
      const int swz = ((c & 3) ^ (rr & 3) ^ ((rr >> 2) & 3)) * 8;
      const int cc = (c & 3) * 8;
      float s8[8] = {};
#pragma unroll
      for (int kc = 0; kc < PHS_KS; ++kc) {
        bf16x8 v = *reinterpret_cast<const bf16x8*>(
            At + (long)kc * NB + (long)rr * HIDDEN + k0 + cc);
#pragma unroll
        for (int j = 0; j < 8; ++j) s8[j] += (float)v[j];
      }
      const float inv = h ? inv1 : inv0;
      bf16x8 o;
#pragma unroll
      for (int j = 0; j < 8; ++j) o[j] = (bf16)(s8[j] * inv);
      *reinterpret_cast<bf16x8*>(dA + rr * 32 + swz) = o;
      GLOAD16(Bt + (long)rr * HIDDEN + k0 + swz, (char*)dB + c * 16);
    }
  };

  const int nt = HIDDEN / 32;  // 24
  STAGE(0, 0);
  __syncthreads();

  f32x4 acc[4][4] = {};
  int cur = 0;
#pragma unroll 1
  for (int t = 0; t < nt; ++t) {
    if (t + 1 < nt) STAGE(cur ^ 1, (t + 1) * 32);
    const bf16* rA = smem + cur * 4096;
    const bf16* rB = smem + 8192 + cur * 4096;
    bf16x8 af[4], bfr[4];
#pragma unroll
    for (int m = 0; m < 4; ++m)
      af[m] = *reinterpret_cast<const bf16x8*>(&rA[(wr * 64 + m * 16 + lr) * 32 + sl]);
#pragma unroll
    for (int n = 0; n < 4; ++n)
      bfr[n] = *reinterpret_cast<const bf16x8*>(&rB[(wc * 64 + n * 16 + lr) * 32 + sl]);
#pragma unroll
    for (int m = 0; m < 4; ++m)
#pragma unroll
      for (int n = 0; n < 4; ++n)
        acc[m][n] = MFMA_BF16(af[m], bfr[n], acc[m][n], 0, 0, 0);
    __syncthreads();
    cur ^= 1;
  }

#pragma unroll
  for (int m = 0; m < 4; ++m)
#pragma unroll
    for (int n = 0; n < 4; ++n) {
      const int gc = col * 128 + wc * 64 + n * 16 + lr;
      const float bv = bias[gc];
#pragma unroll
      for (int j = 0; j < 4; ++j) {
        const int gr = row * 128 + wr * 64 + m * 16 + lg + j;
        out[(long)gr * HIDDEN + gc] = acc[m][n][j] + bv;
      }
    }
}

// ---------------------------------------------------------------------------
extern "C" void kernel_launch(void* const* d_in, const int* in_sizes, int n_in,
                              void* d_out, int out_size, void* d_ws, size_t ws_size,
                              hipStream_t stream) {
  const float* hs = (const float*)d_in[0];    // [B,S,H]
  const float* qu = (const float*)d_in[1];    // [B,Q,H]
  const float* mask = (const float*)d_in[2];  // [B,S]
  const float* Wq = (const float*)d_in[3];
  const float* bq = (const float*)d_in[4];
  const float* Wk = (const float*)d_in[5];
  const float* Wv = (const float*)d_in[7];
  const float* bv = (const float*)d_in[8];
  float* out = (float*)d_out;  // [B,Q,H] fp32
  // bk (d_in[6]) adds a softmax-row-constant -> cancels exactly.

  const size_t HS_N = (size_t)BATCH * SEQ * HIDDEN;
  const size_t QU_N = (size_t)BATCH * NQ * HIDDEN;
  const size_t W_N = (size_t)HIDDEN * HIDDEN;
  const size_t P_N = (size_t)BATCH * NQ * SEQ;

  char* ws = (char*)d_ws;
  size_t off = 0;
  auto alloc = [&](size_t bytes) {
    char* p = ws + off;
    off += (bytes + 255) & ~(size_t)255;
    return p;
  };

  // regionA: hsb (live through scores) / PHS partials (after) — overlap
  char* regionA = alloc(HS_N * 2);
  bf16* hsb = (bf16*)regionA;
  bf16* Ppart = (bf16*)regionA;        // PHS_KS(4) * QU_N bf16 = 25.2 MB
  u8* hsT8 = (u8*)alloc(HS_N);         // [B][H][S] fp8 e4m3
  u8* Pr = (u8*)alloc(P_N);            // unnormalized probs exp(s+mb), fp8
  bf16* qub = (bf16*)alloc(QU_N * 2);
  bf16* tmpb = (bf16*)alloc(QU_N * 2); // folded query: qu.(Wq.Wk^T) + bq.Wk^T
  bf16* Wkb = (bf16*)alloc(W_N * 2);
  bf16* Wqb = (bf16*)alloc(W_N * 2);
  bf16* WvT = (bf16*)alloc(W_N * 2);
  bf16* Mt = (bf16*)alloc(W_N * 2);    // Wk.Wq^T
  float* bqk = (float*)alloc(HIDDEN * 4);
  float* rspart = (float*)alloc((size_t)BATCH * NQ * 128 * 4);  // 2 MB
  float* rowsum = (float*)alloc((size_t)BATCH * NQ * 4);

  // 1) fused prep (qu cvt, Wk/Wq cvt, Wv transpose, bqk gemv) + hs prep
  k_prep<<<dim3(576, 4), dim3(256), 0, stream>>>(qu, qub, Wk, Wkb, Wq, Wqb,
                                                 Wv, WvT, bq, bqk);
  k_cvt_hs_dual<<<dim3(12, 1024), dim3(256), 0, stream>>>(hs, hsb, hsT8);

  // 2) Mt = Wk.Wq^T  [768x768]
  k_gemm_bt<bf16><<<dim3(36), dim3(256), 0, stream>>>(
      Wkb, Wqb, Mt, nullptr, HIDDEN, HIDDEN, 1.0f, 6, 6, 0, 0, 0);

  // 3) folded query: tmp = qub.Mt^T + bqk  [4096x768]
  k_gemm_bt<bf16><<<dim3(192), dim3(256), 0, stream>>>(
      qub, Mt, tmpb, bqk, HIDDEN, HIDDEN, 1.0f, 6, 32, 0, 0, 0);

  // 4) scores (256x128, BK=32, 2 blocks/CU): Pr(fp8) = exp2(...), rowsum partials
  const float qkscale = 1.0f / sqrtf((float)HIDDEN);
  k_score256<<<dim3(1024), dim3(512), 0, stream>>>(tmpb, hsb, Pr, mask, rspart, qkscale);
  k_rowsum<<<dim3(BATCH * NQ / 8), dim3(256), 0, stream>>>(rspart, rowsum);

  // 5) PHS partials (fp8 MFMA): Ppart[kc] = P8[:, kc-chunk] . hsT8^T
  k_gemm_phs<<<dim3(6 * 8 * 4 * PHS_KS), dim3(256), 0, stream>>>(Pr, hsT8, Ppart);

  // 6) V-fold with inline reduce+normalize: out = ((sum Ppart)/rowsum).Wv + bv
  k_vfold<<<dim3(192), dim3(256), 0, stream>>>(Ppart, rowsum, WvT, bv, out);
}